// Round 2
// baseline (75.749 us; speedup 1.0000x reference)
//
#include <hip/hip_runtime.h>
#include <hip/hip_bf16.h>

#define NB 16
#define N_IN 512
#define N_OUT 4096
#define OUT_CH 64
#define M_TILE 64
#define NCHUNK 4                 // 256 threads / 64 m-values
#define NPER (N_IN / NCHUNK)     // 128 n per thread

__global__ __launch_bounds__(256) void convdeepset_kernel(
    const float* __restrict__ x,
    const float* __restrict__ y,
    const float* __restrict__ t,
    const float* __restrict__ sigma,
    const float* __restrict__ W,
    const float* __restrict__ bias,
    float* __restrict__ out)
{
    __shared__ float xs[N_IN];
    __shared__ float ys[N_IN];
    __shared__ float red0[256];
    __shared__ float red1[256];
    __shared__ float f0[M_TILE];
    __shared__ float f1[M_TILE];
    __shared__ float wf[OUT_CH * 2];
    __shared__ float bf[OUT_CH];

    const int tid = threadIdx.x;
    const int blk = blockIdx.x;       // b * (N_OUT/M_TILE) + mtile
    const int b   = blk >> 6;         // N_OUT/M_TILE == 64
    const int mt  = blk & 63;
    const int m0  = mt * M_TILE;

    // stage x, y into LDS
    for (int i = tid; i < N_IN; i += 256) {
        xs[i] = x[b * N_IN + i];
        ys[i] = y[b * N_IN + i];
    }
    if (tid < OUT_CH * 2) wf[tid] = W[tid];
    if (tid < OUT_CH)     bf[tid] = bias[tid];
    __syncthreads();

    const int ml = tid & 63;          // which m within the tile
    const int nc = tid >> 6;          // which n-chunk (== wave id)
    const int m  = m0 + ml;
    const float tm = t[b * N_OUT + m];

    // k_c = -0.5 / exp(sigma_c)^2, with log2(e) folded in for exp2
    const float LOG2E = 1.4426950408889634f;
    const float s0 = sigma[0];
    const float s1 = sigma[1];
    const float k0 = -0.5f * __builtin_amdgcn_exp2f(-2.0f * s0 * LOG2E) * LOG2E;
    const float k1 = -0.5f * __builtin_amdgcn_exp2f(-2.0f * s1 * LOG2E) * LOG2E;

    float a0 = 0.0f, a1 = 0.0f;
    const int nbase = nc * NPER;

    if (k0 == k1) {
        // fast path: both length scales identical (true for the given data) -> 1 exp/pair
        #pragma unroll 8
        for (int i = 0; i < NPER; ++i) {
            float dx = xs[nbase + i] - tm;
            float e  = __builtin_amdgcn_exp2f(k0 * dx * dx);
            a0 += e;
            a1 = fmaf(ys[nbase + i], e, a1);
        }
    } else {
        #pragma unroll 8
        for (int i = 0; i < NPER; ++i) {
            float dx = xs[nbase + i] - tm;
            float d2 = dx * dx;
            a0 += __builtin_amdgcn_exp2f(k0 * d2);
            a1 = fmaf(ys[nbase + i], __builtin_amdgcn_exp2f(k1 * d2), a1);
        }
    }

    red0[tid] = a0;
    red1[tid] = a1;
    __syncthreads();

    if (tid < M_TILE) {
        float dens = red0[tid] + red0[tid + 64] + red0[tid + 128] + red0[tid + 192];
        float conv = red1[tid] + red1[tid + 64] + red1[tid + 128] + red1[tid + 192];
        f0[tid] = dens;
        f1[tid] = conv / (dens + 1e-8f);
    }
    __syncthreads();

    // epilogue: out[b, m, o] = W[o,0]*dens + W[o,1]*normalized + b[o]
    // 64 m * 64 o fp32 per block; float4 stores (coalesced, 16B/lane)
    const size_t obase = (size_t)(b * N_OUT + m0) * OUT_CH;
    for (int p = tid; p < M_TILE * OUT_CH / 4; p += 256) {
        int mloc = p >> 4;            // 16 float4s per m
        int o    = (p & 15) * 4;
        float d = f0[mloc], nrm = f1[mloc];
        float4 v;
        v.x = fmaf(wf[2 * (o + 0) + 0], d, fmaf(wf[2 * (o + 0) + 1], nrm, bf[o + 0]));
        v.y = fmaf(wf[2 * (o + 1) + 0], d, fmaf(wf[2 * (o + 1) + 1], nrm, bf[o + 1]));
        v.z = fmaf(wf[2 * (o + 2) + 0], d, fmaf(wf[2 * (o + 2) + 1], nrm, bf[o + 2]));
        v.w = fmaf(wf[2 * (o + 3) + 0], d, fmaf(wf[2 * (o + 3) + 1], nrm, bf[o + 3]));
        *reinterpret_cast<float4*>(out + obase + (size_t)mloc * OUT_CH + o) = v;
    }
}

extern "C" void kernel_launch(void* const* d_in, const int* in_sizes, int n_in,
                              void* d_out, int out_size, void* d_ws, size_t ws_size,
                              hipStream_t stream) {
    const float* x     = (const float*)d_in[0];
    const float* y     = (const float*)d_in[1];
    const float* t     = (const float*)d_in[2];
    const float* sigma = (const float*)d_in[3];
    const float* W     = (const float*)d_in[4];
    const float* bias  = (const float*)d_in[5];
    float* out = (float*)d_out;

    dim3 grid(NB * (N_OUT / M_TILE));   // 16 * 64 = 1024 blocks
    convdeepset_kernel<<<grid, 256, 0, stream>>>(x, y, t, sigma, W, bias, out);
}